// Round 1
// baseline (102.902 us; speedup 1.0000x reference)
//
#include <hip/hip_runtime.h>
#include <math.h>

#define N 256
#define D 512

// ---------------------------------------------------------------------------
// ws layout (floats):
//   [0..1]   : accumulators (dist_sum, angle_sum)
//   [64..]   : Gs  (N*N)
//   then Gt  (N*N), Ss (N), St (N)
// total ~526 KB
// ---------------------------------------------------------------------------

// Gram: G = E * E^T, E is N x D.  grid (16,16,2), block (16,16).
__global__ void gram_kernel(const float* __restrict__ Es,
                            const float* __restrict__ Et,
                            float* __restrict__ Gs,
                            float* __restrict__ Gt) {
    const float* E = blockIdx.z ? Et : Es;
    float* G = blockIdx.z ? Gt : Gs;
    __shared__ float As[16][17];
    __shared__ float Bs[16][17];
    const int tx = threadIdx.x, ty = threadIdx.y;
    const int row = blockIdx.y * 16 + ty;   // output row
    const int colr = blockIdx.x * 16 + ty;  // row fetched for the B tile
    float acc = 0.f;
    for (int k0 = 0; k0 < D; k0 += 16) {
        As[ty][tx] = E[row * D + k0 + tx];
        Bs[ty][tx] = E[colr * D + k0 + tx];
        __syncthreads();
#pragma unroll
        for (int kk = 0; kk < 16; ++kk)
            acc += As[ty][kk] * Bs[tx][kk];
        __syncthreads();
    }
    G[row * N + blockIdx.x * 16 + tx] = acc;
}

// Row sums S_i = sum_d E[i,d].  grid (N,2), block 64 (one wave).
__global__ void rowsum_kernel(const float* __restrict__ Es,
                              const float* __restrict__ Et,
                              float* __restrict__ Ss,
                              float* __restrict__ St) {
    const float* E = blockIdx.y ? Et : Es;
    float* S = blockIdx.y ? St : Ss;
    const int row = blockIdx.x;
    const int t = threadIdx.x;
    float s = 0.f;
    for (int d = t; d < D; d += 64) s += E[row * D + d];
#pragma unroll
    for (int off = 32; off > 0; off >>= 1) s += __shfl_down(s, off);
    if (t == 0) S[row] = s;
}

__device__ __forceinline__ float smooth_l1(float x) {
    float ax = fabsf(x);
    return ax < 1.f ? 0.5f * ax * ax : ax - 0.5f;
}

// Distance loss partial sum over i<j.  grid N, block N (thread j, block i).
__global__ void dist_kernel(const float* __restrict__ Gs,
                            const float* __restrict__ Gt,
                            const float* __restrict__ Ss,
                            const float* __restrict__ St,
                            float* __restrict__ acc) {
    const int i = blockIdx.x;
    const int j = threadIdx.x;
    float v = 0.f;
    if (i < j) {
        // ||e_i - e_j + eps||^2 = ||e_i - e_j||^2 + 2 eps (S_i - S_j) + D eps^2
        const float epsc = (float)((double)D * 1e-12);
        float ds2 = Gs[i * N + i] - 2.f * Gs[i * N + j] + Gs[j * N + j]
                    + 2e-6f * (Ss[i] - Ss[j]) + epsc;
        float dt2 = Gt[i * N + i] - 2.f * Gt[i * N + j] + Gt[j * N + j]
                    + 2e-6f * (St[i] - St[j]) + epsc;
        v = smooth_l1(sqrtf(ds2) - sqrtf(dt2));
    }
    __shared__ float red[256];
    red[j] = v;
    __syncthreads();
    for (int s = 128; s > 0; s >>= 1) {
        if (j < s) red[j] += red[j + s];
        __syncthreads();
    }
    if (j == 0) atomicAdd(&acc[0], red[0]);
}

// Angle loss: one block per vertex j (j = blockIdx.x + 1, j in [1,254]).
// Triplets i < j < k, flattened pair index p -> (i,k) for load balance.
__global__ void angle_kernel(const float* __restrict__ Gs,
                             const float* __restrict__ Gt,
                             float* __restrict__ acc) {
    const int j = blockIdx.x + 1;
    const int tid = threadIdx.x;
    __shared__ float cs[N], ct[N], rns[N], rnt[N];
    const float Gsjj = Gs[j * N + j];
    const float Gtjj = Gt[j * N + j];

    // column j of each Gram + reciprocal norms of (e_a - e_j)
    {
        float cja = Gs[tid * N + j];
        float cjb = Gt[tid * N + j];
        cs[tid] = cja;
        ct[tid] = cjb;
        float n2s = Gs[tid * N + tid] - 2.f * cja + Gsjj;
        float n2t = Gt[tid * N + tid] - 2.f * cjb + Gtjj;
        rns[tid] = (tid == j) ? 0.f : 1.f / sqrtf(n2s);
        rnt[tid] = (tid == j) ? 0.f : 1.f / sqrtf(n2t);
    }
    __syncthreads();

    const int nk = 255 - j;       // k in [j+1, 255]
    const int npairs = j * nk;    // i in [0, j)
    const float lo = (float)(-1.0 + 1e-7);
    const float hi = (float)(1.0 - 1e-7);

    float partial = 0.f;
    for (int p = tid; p < npairs; p += 256) {
        int i = p / nk;
        int k = j + 1 + (p - i * nk);
        float dots = Gs[i * N + k] - cs[i] - cs[k] + Gsjj;
        float dott = Gt[i * N + k] - ct[i] - ct[k] + Gtjj;
        float coss = dots * rns[i] * rns[k];
        float cost = dott * rnt[i] * rnt[k];
        coss = fminf(fmaxf(coss, lo), hi);
        cost = fminf(fmaxf(cost, lo), hi);
        partial += smooth_l1(acosf(coss) - acosf(cost));
    }

    __shared__ float red[256];
    red[tid] = partial;
    __syncthreads();
    for (int s = 128; s > 0; s >>= 1) {
        if (tid < s) red[tid] += red[tid + s];
        __syncthreads();
    }
    if (tid == 0) atomicAdd(&acc[1], red[0]);
}

__global__ void finalize_kernel(const float* __restrict__ acc,
                                float* __restrict__ out) {
    float dl = 2.f * acc[0] / (float)(N * N);                    // full-matrix mean
    float al = acc[1] / (float)(N * (N - 1) * (N - 2) / 6);      // C(n,3)
    out[0] = 1.0f * dl + 2.0f * al;
    out[1] = dl;
    out[2] = al;
}

extern "C" void kernel_launch(void* const* d_in, const int* in_sizes, int n_in,
                              void* d_out, int out_size, void* d_ws, size_t ws_size,
                              hipStream_t stream) {
    const float* Es = (const float*)d_in[0];
    const float* Et = (const float*)d_in[1];
    float* out = (float*)d_out;
    float* ws = (float*)d_ws;

    float* acc = ws;              // 2 floats
    float* Gs  = ws + 64;
    float* Gt  = Gs + N * N;
    float* Ss  = Gt + N * N;
    float* St  = Ss + N;

    hipMemsetAsync(acc, 0, 2 * sizeof(float), stream);
    gram_kernel<<<dim3(16, 16, 2), dim3(16, 16), 0, stream>>>(Es, Et, Gs, Gt);
    rowsum_kernel<<<dim3(N, 2), 64, 0, stream>>>(Es, Et, Ss, St);
    dist_kernel<<<N, N, 0, stream>>>(Gs, Gt, Ss, St, acc);
    angle_kernel<<<N - 2, N, 0, stream>>>(Gs, Gt, acc);
    finalize_kernel<<<1, 1, 0, stream>>>(acc, out);
}

// Round 2
// 87.513 us; speedup vs baseline: 1.1758x; 1.1758x over previous
//
#include <hip/hip_runtime.h>
#include <math.h>

#define N 256
#define D 512
#define KT 64
#define LDSPAD 68   // padded row length (floats): 68*4B=272B, 16B-aligned, conflict-free b128
#define SPLIT 4

__device__ __forceinline__ float smooth_l1(float x) {
    float ax = fabsf(x);
    return ax < 1.f ? 0.5f * ax * ax : ax - 0.5f;
}

// ---------------------------------------------------------------------------
// Gram: G = E * E^T  (N x N from N x D).  grid (16,16,2), block (16,16).
// Block (0,0,0) also zero-inits the accumulators (replaces hipMemsetAsync).
// ---------------------------------------------------------------------------
__global__ __launch_bounds__(256) void gram_kernel(const float* __restrict__ Es,
                                                   const float* __restrict__ Et,
                                                   float* __restrict__ Gs,
                                                   float* __restrict__ Gt,
                                                   float* __restrict__ acc) {
    const float* E = blockIdx.z ? Et : Es;
    float* G = blockIdx.z ? Gt : Gs;
    __shared__ __align__(16) float As[16 * LDSPAD];
    __shared__ __align__(16) float Bs[16 * LDSPAD];
    const int tx = threadIdx.x, ty = threadIdx.y;
    const int t = ty * 16 + tx;
    if (blockIdx.x == 0 && blockIdx.y == 0 && blockIdx.z == 0 && t == 0) {
        acc[0] = 0.f;
        acc[1] = 0.f;
    }
    const int lr = t >> 4;          // tile row this thread loads
    const int lc = (t & 15) * 4;    // tile col (float4 granularity)
    const int rowA = blockIdx.y * 16 + lr;
    const int rowB = blockIdx.x * 16 + lr;
    float sum = 0.f;
    for (int k0 = 0; k0 < D; k0 += KT) {
        float4 a4 = *(const float4*)&E[rowA * D + k0 + lc];
        float4 b4 = *(const float4*)&E[rowB * D + k0 + lc];
        *(float4*)&As[lr * LDSPAD + lc] = a4;
        *(float4*)&Bs[lr * LDSPAD + lc] = b4;
        __syncthreads();
        const float4* Ar = (const float4*)&As[ty * LDSPAD];
        const float4* Br = (const float4*)&Bs[tx * LDSPAD];
#pragma unroll
        for (int kk = 0; kk < KT / 4; ++kk) {
            float4 a = Ar[kk], b = Br[kk];
            sum += a.x * b.x + a.y * b.y + a.z * b.z + a.w * b.w;
        }
        __syncthreads();
    }
    G[(blockIdx.y * 16 + ty) * N + blockIdx.x * 16 + tx] = sum;
}

// ---------------------------------------------------------------------------
// Fused angle + distance loss.
// grid (255, SPLIT), block 256.  j = blockIdx.x + 1 in [1,255].
//   - dist: pairs (i, j), i<j, computed by split 0 only (free: reuses norms)
//   - angle: triplets i<j<k, flat pair index p -> (i,k), strided over splits
// Norm^2(e_a - e_j) = G[a,a] - 2 G[a,j] + G[j,j]; dot via Gram recombination.
// eps_pd correction (~2e-6 on the loss) dropped; eps_cos floor unreachable.
// ---------------------------------------------------------------------------
__global__ __launch_bounds__(256) void angle_dist_kernel(const float* __restrict__ Gs,
                                                         const float* __restrict__ Gt,
                                                         float* __restrict__ acc) {
    const int j = blockIdx.x + 1;   // 1..255
    const int tid = threadIdx.x;
    __shared__ float cs[N], ct[N], rns[N], rnt[N];
    __shared__ float2 red[256];
    const float Gsjj = Gs[j * N + j];
    const float Gtjj = Gt[j * N + j];

    float distp = 0.f;
    {
        const int a = tid;
        float cja = Gs[a * N + j];
        float cjb = Gt[a * N + j];
        cs[a] = cja;
        ct[a] = cjb;
        float n2s = Gs[a * N + a] - 2.f * cja + Gsjj;
        float n2t = Gt[a * N + a] - 2.f * cjb + Gtjj;
        float rs = (a == j) ? 0.f : rsqrtf(n2s);
        float rt = (a == j) ? 0.f : rsqrtf(n2t);
        rns[a] = rs;
        rnt[a] = rt;
        if (blockIdx.y == 0 && a < j) {
            // sqrt(n2) = n2 * rsqrt(n2)
            distp = smooth_l1(n2s * rs - n2t * rt);
        }
    }
    __syncthreads();

    const int nk = 255 - j;         // k in [j+1, 255]
    const int npairs = j * nk;      // i in [0, j)
    const float inv_nk = 1.0f / (float)nk;   // inf when nk==0; loop is empty then
    const float lo = -0.99999994f;  // -(1 - 1e-7) in fp32
    const float hi = 0.99999994f;

    float anglep = 0.f;
    for (int p = blockIdx.y * 256 + tid; p < npairs; p += 256 * SPLIT) {
        int i = (int)((float)p * inv_nk);
        int rem = p - i * nk;
        if (rem < 0) { --i; rem += nk; }
        else if (rem >= nk) { ++i; rem -= nk; }
        const int k = j + 1 + rem;
        float dots = Gs[i * N + k] - cs[i] - cs[k] + Gsjj;
        float dott = Gt[i * N + k] - ct[i] - ct[k] + Gtjj;
        float coss = dots * (rns[i] * rns[k]);
        float cost = dott * (rnt[i] * rnt[k]);
        coss = fminf(fmaxf(coss, lo), hi);
        cost = fminf(fmaxf(cost, lo), hi);
        anglep += smooth_l1(acosf(coss) - acosf(cost));
    }

    red[tid] = make_float2(distp, anglep);
    __syncthreads();
    for (int s = 128; s > 0; s >>= 1) {
        if (tid < s) {
            red[tid].x += red[tid + s].x;
            red[tid].y += red[tid + s].y;
        }
        __syncthreads();
    }
    if (tid == 0) {
        atomicAdd(&acc[1], red[0].y);
        if (blockIdx.y == 0) atomicAdd(&acc[0], red[0].x);
    }
}

__global__ void finalize_kernel(const float* __restrict__ acc,
                                float* __restrict__ out) {
    float dl = 2.f * acc[0] / (float)(N * N);                 // mean over full n x n
    float al = acc[1] / (float)(N * (N - 1) * (N - 2) / 6);   // C(n,3) triplets
    out[0] = 1.0f * dl + 2.0f * al;
    out[1] = dl;
    out[2] = al;
}

extern "C" void kernel_launch(void* const* d_in, const int* in_sizes, int n_in,
                              void* d_out, int out_size, void* d_ws, size_t ws_size,
                              hipStream_t stream) {
    const float* Es = (const float*)d_in[0];
    const float* Et = (const float*)d_in[1];
    float* out = (float*)d_out;
    float* ws = (float*)d_ws;

    float* acc = ws;              // 2 floats
    float* Gs  = ws + 64;
    float* Gt  = Gs + N * N;

    gram_kernel<<<dim3(16, 16, 2), dim3(16, 16), 0, stream>>>(Es, Et, Gs, Gt, acc);
    angle_dist_kernel<<<dim3(N - 1, SPLIT), 256, 0, stream>>>(Gs, Gt, acc);
    finalize_kernel<<<1, 1, 0, stream>>>(acc, out);
}